// Round 6
// baseline (438.075 us; speedup 1.0000x reference)
//
#include <hip/hip_runtime.h>
#include <hip/hip_bf16.h>
#include <math.h>

// ---------------------------------------------------------------------------
// GATv2 x2 layers, N=50000, d=128, E=800000 (+N self loops).
// Round 6: CSR fill split into two bucketed phases.
//  - fill was 56us, WRITE_SIZE 55MB = 850k random 4B scatters dirtying a full
//    64B line each (random-scatter write ceiling ~1TB/s).
//  - fill1: scatter (dst,src) 8B into per-64-node bucket regions (bucket
//    cursor seeded from offs inside scan3) -> bucket-sequential writes, ~7MB.
//  - fill2: linear read of ebuf, per-node atomic placement into a ~4KB-local
//    colsrc window -> line-local writes, 3.4MB.
// ---------------------------------------------------------------------------

#define LRELU_ATT 0.2f
#define LRELU_ACT 0.01f

typedef __attribute__((ext_vector_type(8))) short bf16x8;
typedef __attribute__((ext_vector_type(4))) float f32x4;

// ---------------- CSR build ----------------

__global__ void zero_kernel(int* __restrict__ p, int n) {
    int i = blockIdx.x * blockDim.x + threadIdx.x;
    if (i < n) p[i] = 0;
}

__global__ void hist_kernel(const int* __restrict__ ei, int E, int Etot,
                            int* __restrict__ deg) {
    int e = blockIdx.x * blockDim.x + threadIdx.x;
    if (e >= Etot) return;
    int d = (e < E) ? ei[E + e] : (e - E);
    atomicAdd(&deg[d], 1);
}

__global__ void scan1_kernel(const int* __restrict__ deg, int n,
                             int* __restrict__ offs, int* __restrict__ bsum) {
    __shared__ int s[256];
    int tid = threadIdx.x;
    int i = blockIdx.x * 256 + tid;
    int v = (i < n) ? deg[i] : 0;
    s[tid] = v;
    __syncthreads();
    int sum = v;
    #pragma unroll
    for (int d = 1; d < 256; d <<= 1) {
        int t = (tid >= d) ? s[tid - d] : 0;
        __syncthreads();
        sum += t;
        s[tid] = sum;
        __syncthreads();
    }
    if (i < n) offs[i] = sum - v;
    if (tid == 255) bsum[blockIdx.x] = sum;
}

__global__ void scan2_kernel(int* __restrict__ bsum, int nb,
                             int* __restrict__ boff) {
    __shared__ int s[256];
    int tid = threadIdx.x;
    int v = (tid < nb) ? bsum[tid] : 0;
    s[tid] = v;
    __syncthreads();
    int sum = v;
    #pragma unroll
    for (int d = 1; d < 256; d <<= 1) {
        int t = (tid >= d) ? s[tid - d] : 0;
        __syncthreads();
        sum += t;
        s[tid] = sum;
        __syncthreads();
    }
    if (tid < nb) boff[tid] = sum - v;
}

__global__ void scan3_kernel(int* __restrict__ offs, const int* __restrict__ boff,
                             int n, int Etot, int* __restrict__ cursor,
                             int* __restrict__ bcur) {
    int i = blockIdx.x * 256 + threadIdx.x;
    if (i < n) {
        int o = offs[i] + boff[blockIdx.x];
        offs[i] = o;
        cursor[i] = o;
        if ((i & 63) == 0) bcur[i >> 6] = o;   // bucket = 64 nodes
    }
    if (i == 0) offs[n] = Etot;
}

// fill phase 1: scatter (dst,src) into per-bucket regions (bucket-sequential).
__global__ void fill1_kernel(const int* __restrict__ ei, int E, int Etot,
                             int* __restrict__ bcur, uint2* __restrict__ ebuf) {
    int e = blockIdx.x * blockDim.x + threadIdx.x;
    if (e >= Etot) return;
    int s, d;
    if (e < E) { s = ei[e]; d = ei[E + e]; }
    else       { s = d = e - E; }
    int pos = atomicAdd(&bcur[d >> 6], 1);
    ebuf[pos] = make_uint2((unsigned)d, (unsigned)s);
}

// fill phase 2: linear read, place src at per-node cursor (line-local writes).
__global__ void fill2_kernel(const uint2* __restrict__ ebuf, int Etot,
                             int* __restrict__ cursor, int* __restrict__ colsrc) {
    int i = blockIdx.x * blockDim.x + threadIdx.x;
    if (i >= Etot) return;
    uint2 q = ebuf[i];
    int pos = atomicAdd(&cursor[q.x], 1);
    colsrc[pos] = (int)q.y;
}

// ---------------- helpers ----------------

__device__ __forceinline__ unsigned short f2bf(float f) {
    unsigned u = __float_as_uint(f);
    unsigned r = (u + 0x7fffu + ((u >> 16) & 1u)) >> 16;   // RNE
    return (unsigned short)r;
}

__device__ __forceinline__ bf16x8 pack8(float4 a, float4 b) {
    union { bf16x8 v; unsigned short u[8]; } t;
    t.u[0] = f2bf(a.x); t.u[1] = f2bf(a.y); t.u[2] = f2bf(a.z); t.u[3] = f2bf(a.w);
    t.u[4] = f2bf(b.x); t.u[5] = f2bf(b.y); t.u[6] = f2bf(b.z); t.u[7] = f2bf(b.w);
    return t.v;
}

__device__ __forceinline__ bf16x8 ldbf8(const unsigned short* p) {
    union { uint4 q; bf16x8 v; } t;
    t.q = *(const uint4*)p;
    return t.v;
}

__device__ __forceinline__ void unpack8(uint4 q, float* v) {
    v[0] = __uint_as_float(q.x << 16); v[1] = __uint_as_float(q.x & 0xffff0000u);
    v[2] = __uint_as_float(q.y << 16); v[3] = __uint_as_float(q.y & 0xffff0000u);
    v[4] = __uint_as_float(q.z << 16); v[5] = __uint_as_float(q.z & 0xffff0000u);
    v[6] = __uint_as_float(q.w << 16); v[7] = __uint_as_float(q.w & 0xffff0000u);
}

__device__ __forceinline__ float logit8(const float* v, const float* xrv,
                                        const float* attv) {
    float p = 0.f;
    #pragma unroll
    for (int j = 0; j < 8; ++j) {
        float m = v[j] + xrv[j];
        m = m > 0.f ? m : LRELU_ATT * m;
        p = fmaf(m, attv[j], p);
    }
    return p;
}

// ---------------- W pre-swizzle into MFMA B-fragment order ----------------
// B frag for (ks, ct): lane l, elem j holds W[ks*32 + (l>>4)*8 + j][ct*16 + (l&15)].
// Linear frag address: ((ks*8 + ct)*64 + l)*8 + j.  4 matrices: Wl0,Wr0,Wl1,Wr1.

__global__ void wconv_kernel(const float* __restrict__ W0, const float* __restrict__ W1,
                             const float* __restrict__ W2, const float* __restrict__ W3,
                             unsigned short* __restrict__ Wb) {
    int g = blockIdx.x * 256 + threadIdx.x;    // 0 .. 4*16384-1
    int m = g >> 14;
    int f = g & 16383;
    int j = f & 7, l = (f >> 3) & 63, ct = (f >> 9) & 7, ks = f >> 12;
    int row = ks * 32 + ((l >> 4) << 3) + j;
    int col = ct * 16 + (l & 15);
    const float* W = m == 0 ? W0 : m == 1 ? W1 : m == 2 ? W2 : W3;
    Wb[g] = f2bf(W[row * 128 + col]);
}

// ---------------- MFMA dual GEMM: xlb(bf16)=X@Wl+bl ; xr(f32)=X@Wr+br ------
// block = 128 thr = 2 waves; wave = 32 rows x 128 cols, K=128.
// A frags held in registers (8 x bf16x8); B frags streamed from L2 (Wb).

template<bool INF32>
__global__ __launch_bounds__(128) void gemm_mfma_kernel(
    const void* __restrict__ Xin,
    const unsigned short* __restrict__ Wb,   // layer base: l frags, then r frags
    const float* __restrict__ bl, const float* __restrict__ br,
    unsigned short* __restrict__ xlb, float* __restrict__ xr, int n) {
    const int tid  = threadIdx.x;
    const int wave = tid >> 6, lane = tid & 63;
    const int rowbase = blockIdx.x * 64 + wave * 32;
    const int lrow = lane & 15;
    const int kgrp = lane >> 4;

    bf16x8 af[2][4];
    #pragma unroll
    for (int rt = 0; rt < 2; ++rt) {
        const int row = rowbase + rt * 16 + lrow;
        const bool ok = row < n;
        #pragma unroll
        for (int ks = 0; ks < 4; ++ks) {
            const int k0 = ks * 32 + kgrp * 8;
            if (INF32) {
                const float* X = (const float*)Xin;
                float4 a = make_float4(0.f, 0.f, 0.f, 0.f), b = a;
                if (ok) {
                    a = *(const float4*)(X + (size_t)row * 128 + k0);
                    b = *(const float4*)(X + (size_t)row * 128 + k0 + 4);
                }
                af[rt][ks] = pack8(a, b);
            } else {
                const unsigned short* X = (const unsigned short*)Xin;
                union { uint4 q; bf16x8 v; } t;
                t.q = make_uint4(0u, 0u, 0u, 0u);
                if (ok) t.q = *(const uint4*)(X + (size_t)row * 128 + k0);
                af[rt][ks] = t.v;
            }
        }
    }

    #pragma unroll
    for (int m = 0; m < 2; ++m) {
        const unsigned short* wb = Wb + m * 16384;
        f32x4 acc[2][8];
        #pragma unroll
        for (int rt = 0; rt < 2; ++rt)
            #pragma unroll
            for (int ct = 0; ct < 8; ++ct)
                acc[rt][ct] = (f32x4){0.f, 0.f, 0.f, 0.f};

        #pragma unroll
        for (int ct = 0; ct < 8; ++ct) {
            #pragma unroll
            for (int ks = 0; ks < 4; ++ks) {
                bf16x8 bf = ldbf8(wb + ((ks * 8 + ct) * 64 + lane) * 8);
                acc[0][ct] = __builtin_amdgcn_mfma_f32_16x16x32_bf16(af[0][ks], bf, acc[0][ct], 0, 0, 0);
                acc[1][ct] = __builtin_amdgcn_mfma_f32_16x16x32_bf16(af[1][ks], bf, acc[1][ct], 0, 0, 0);
            }
        }

        const float* bias = m ? br : bl;
        #pragma unroll
        for (int rt = 0; rt < 2; ++rt) {
            #pragma unroll
            for (int ct = 0; ct < 8; ++ct) {
                const int col = ct * 16 + lrow;           // D: col = lane&15
                const float bv = bias[col];
                #pragma unroll
                for (int i = 0; i < 4; ++i) {
                    const int row = rowbase + rt * 16 + kgrp * 4 + i;  // D: row=(lane>>4)*4+i
                    if (row < n) {
                        float v = acc[rt][ct][i] + bv;
                        if (m == 0) xlb[(size_t)row * 128 + col] = f2bf(v);
                        else        xr [(size_t)row * 128 + col] = v;
                    }
                }
            }
        }
    }
}

// ---------------- fused attention + aggregation ----------------
// 4 dst nodes per wave: 16-lane subgroup per node, lane owns 8 channels.
// OUTBF: write bf16 (inter-layer h, with leaky 0.01); else f32 (final out).

template<bool OUTBF>
__global__ __launch_bounds__(256) void gat_agg_kernel(
    const unsigned short* __restrict__ xlb, const float* __restrict__ xr,
    const float* __restrict__ att, const float* __restrict__ bo,
    const int* __restrict__ offs, const int* __restrict__ col,
    float* __restrict__ outf, unsigned short* __restrict__ outb,
    int n, int apply_act) {
    const int lane = threadIdx.x & 63;
    const int sub  = lane >> 4;
    const int sl   = lane & 15;
    const int gw   = (blockIdx.x * blockDim.x + threadIdx.x) >> 6;
    const int node = gw * 4 + sub;
    const bool valid = node < n;

    const float4* xr4  = (const float4*)xr;
    const float4* att4 = (const float4*)att;
    float xrv[8], attv[8];
    {
        float4 a = make_float4(0.f, 0.f, 0.f, 0.f), b = a;
        if (valid) {
            a = xr4[(size_t)node * 32 + sl * 2];
            b = xr4[(size_t)node * 32 + sl * 2 + 1];
        }
        xrv[0]=a.x; xrv[1]=a.y; xrv[2]=a.z; xrv[3]=a.w;
        xrv[4]=b.x; xrv[5]=b.y; xrv[6]=b.z; xrv[7]=b.w;
        float4 c = att4[sl * 2], d = att4[sl * 2 + 1];
        attv[0]=c.x; attv[1]=c.y; attv[2]=c.z; attv[3]=c.w;
        attv[4]=d.x; attv[5]=d.y; attv[6]=d.z; attv[7]=d.w;
    }

    float acc[8];
    #pragma unroll
    for (int j = 0; j < 8; ++j) acc[j] = 0.f;
    float den = 0.f;

    int b = 0, cnt = 0;
    if (valid) { b = offs[node]; cnt = offs[node + 1] - b; }
    const uint4* xq = (const uint4*)xlb;

    int t = 0;
    for (; t + 2 <= cnt; t += 2) {
        const int s0 = col[b + t], s1 = col[b + t + 1];
        uint4 q0 = xq[(size_t)s0 * 16 + sl];
        uint4 q1 = xq[(size_t)s1 * 16 + sl];
        float v0[8], v1[8];
        unpack8(q0, v0);
        unpack8(q1, v1);
        float p0 = logit8(v0, xrv, attv);
        float p1 = logit8(v1, xrv, attv);
        p0 += __shfl_xor(p0, 1, 64);  p1 += __shfl_xor(p1, 1, 64);
        p0 += __shfl_xor(p0, 2, 64);  p1 += __shfl_xor(p1, 2, 64);
        p0 += __shfl_xor(p0, 4, 64);  p1 += __shfl_xor(p1, 4, 64);
        p0 += __shfl_xor(p0, 8, 64);  p1 += __shfl_xor(p1, 8, 64);
        const float e0 = __expf(p0), e1 = __expf(p1);
        #pragma unroll
        for (int j = 0; j < 8; ++j)
            acc[j] = fmaf(e1, v1[j], fmaf(e0, v0[j], acc[j]));
        den += e0 + e1;
    }
    if (t < cnt) {
        const int s0 = col[b + t];
        uint4 q0 = xq[(size_t)s0 * 16 + sl];
        float v0[8];
        unpack8(q0, v0);
        float p0 = logit8(v0, xrv, attv);
        p0 += __shfl_xor(p0, 1, 64);
        p0 += __shfl_xor(p0, 2, 64);
        p0 += __shfl_xor(p0, 4, 64);
        p0 += __shfl_xor(p0, 8, 64);
        const float e0 = __expf(p0);
        #pragma unroll
        for (int j = 0; j < 8; ++j) acc[j] = fmaf(e0, v0[j], acc[j]);
        den += e0;
    }

    if (valid) {
        const float inv = 1.f / (den + 1e-16f);
        float4 b1 = ((const float4*)bo)[sl * 2];
        float4 b2 = ((const float4*)bo)[sl * 2 + 1];
        float bov[8] = {b1.x, b1.y, b1.z, b1.w, b2.x, b2.y, b2.z, b2.w};
        float o[8];
        #pragma unroll
        for (int j = 0; j < 8; ++j) {
            float v = acc[j] * inv + bov[j];
            if (apply_act) v = v > 0.f ? v : LRELU_ACT * v;
            o[j] = v;
        }
        if (OUTBF) {
            ushort4 u0, u1;
            u0.x = f2bf(o[0]); u0.y = f2bf(o[1]); u0.z = f2bf(o[2]); u0.w = f2bf(o[3]);
            u1.x = f2bf(o[4]); u1.y = f2bf(o[5]); u1.z = f2bf(o[6]); u1.w = f2bf(o[7]);
            ushort4* ob = (ushort4*)(outb + (size_t)node * 128 + sl * 8);
            ob[0] = u0; ob[1] = u1;
        } else {
            float4* o4 = (float4*)(outf + (size_t)node * 128 + sl * 8);
            o4[0] = make_float4(o[0], o[1], o[2], o[3]);
            o4[1] = make_float4(o[4], o[5], o[6], o[7]);
        }
    }
}

// ---------------- host launch ----------------

static inline size_t align_up(size_t x, size_t a) { return (x + a - 1) & ~(a - 1); }

extern "C" void kernel_launch(void* const* d_in, const int* in_sizes, int n_in,
                              void* d_out, int out_size, void* d_ws, size_t ws_size,
                              hipStream_t stream) {
    const float* x   = (const float*)d_in[0];
    const int*   ei  = (const int*)d_in[1];     // int32 per harness contract
    const float* Wl0 = (const float*)d_in[2];
    const float* bl0 = (const float*)d_in[3];
    const float* Wr0 = (const float*)d_in[4];
    const float* br0 = (const float*)d_in[5];
    const float* att0= (const float*)d_in[6];
    const float* bo0 = (const float*)d_in[7];
    const float* Wl1 = (const float*)d_in[8];
    const float* bl1 = (const float*)d_in[9];
    const float* Wr1 = (const float*)d_in[10];
    const float* br1 = (const float*)d_in[11];
    const float* att1= (const float*)d_in[12];
    const float* bo1 = (const float*)d_in[13];
    float* outp = (float*)d_out;

    const int N    = in_sizes[0] / 128;
    const int E    = in_sizes[1] / 2;
    const int Etot = E + N;
    const int NB   = (N + 63) / 64;          // 64-node buckets

    // workspace layout (~53 MB)
    char* p = (char*)d_ws;
    size_t off = 0;
    unsigned short* xlb = (unsigned short*)(p + off);
    off = align_up(off + (size_t)N * 128 * 2, 256);
    float* xr = (float*)(p + off);
    off = align_up(off + (size_t)N * 128 * 4, 256);
    unsigned short* Wb = (unsigned short*)(p + off);
    off = align_up(off + (size_t)4 * 16384 * 2, 256);
    int* degcur = (int*)(p + off); off = align_up(off + (size_t)N * 4, 256);
    int* offs   = (int*)(p + off); off = align_up(off + (size_t)(N + 1) * 4, 256);
    int* bsum   = (int*)(p + off); off = align_up(off + 256 * 4, 256);
    int* boff   = (int*)(p + off); off = align_up(off + 256 * 4, 256);
    int* bcur   = (int*)(p + off); off = align_up(off + (size_t)NB * 4, 256);
    int* colsrc = (int*)(p + off); off = align_up(off + (size_t)Etot * 4, 256);
    uint2* ebuf = (uint2*)(p + off); off = align_up(off + (size_t)Etot * 8, 256);
    unsigned short* hb = (unsigned short*)d_out;   // inter-layer bf16 h
    (void)ws_size;

    const int nbScan = (N + 255) / 256;
    const int nbEdge = (Etot + 255) / 256;

    // ---- CSR build + W swizzle ----
    zero_kernel<<<nbScan, 256, 0, stream>>>(degcur, N);
    hist_kernel<<<nbEdge, 256, 0, stream>>>(ei, E, Etot, degcur);
    scan1_kernel<<<nbScan, 256, 0, stream>>>(degcur, N, offs, bsum);
    scan2_kernel<<<1, 256, 0, stream>>>(bsum, nbScan, boff);
    scan3_kernel<<<nbScan, 256, 0, stream>>>(offs, boff, N, Etot, degcur, bcur);
    fill1_kernel<<<nbEdge, 256, 0, stream>>>(ei, E, Etot, bcur, ebuf);
    fill2_kernel<<<nbEdge, 256, 0, stream>>>(ebuf, Etot, degcur, colsrc);
    wconv_kernel<<<256, 256, 0, stream>>>(Wl0, Wr0, Wl1, Wr1, Wb);

    const int nbGemm = (N + 63) / 64;
    const int nbAgg  = (N + 15) / 16;

    // ---- layer 0 ----
    gemm_mfma_kernel<true><<<nbGemm, 128, 0, stream>>>(
        (const void*)x, Wb, bl0, br0, xlb, xr, N);
    gat_agg_kernel<true><<<nbAgg, 256, 0, stream>>>(
        xlb, xr, att0, bo0, offs, colsrc, nullptr, hb, N, 1);

    // ---- layer 1 ----
    gemm_mfma_kernel<false><<<nbGemm, 128, 0, stream>>>(
        (const void*)hb, Wb + 2 * 16384, bl1, br1, xlb, xr, N);
    gat_agg_kernel<false><<<nbAgg, 256, 0, stream>>>(
        xlb, xr, att1, bo1, offs, colsrc, outp, nullptr, N, 0);
}

// Round 7
// 272.157 us; speedup vs baseline: 1.6096x; 1.6096x over previous
//
#include <hip/hip_runtime.h>
#include <hip/hip_bf16.h>
#include <math.h>

// ---------------------------------------------------------------------------
// GATv2 x2 layers, N=50000, d=128, E=800000 (+N self loops).
// Round 7: CSR fill via privatized counting sort (no hot atomics, line-local
// writes). Round-6 lesson: 782 bucket cursors x ~1087 serialized RMWs = 218us;
// contention depth, not write traffic, dominated.
//  - histA: per-block LDS histogram over 196 buckets (dst>>8), no contention.
//  - scanM: per-bucket scan over block counts, seeded with offs[b*256]
//           -> disjoint per-(block,bucket) slices of ebuf.
//  - scatter: LDS cursors, each block writes its own contiguous slices (~7MB).
//  - order: 1 block/bucket, per-node cursors touched by one block only,
//           colsrc writes land in block-owned ~17KB region.
// Rest identical to round 5 (MFMA GEMM, bf16 xl, 16-lane-subgroup agg).
// ---------------------------------------------------------------------------

#define LRELU_ATT 0.2f
#define LRELU_ACT 0.01f

typedef __attribute__((ext_vector_type(8))) short bf16x8;
typedef __attribute__((ext_vector_type(4))) float f32x4;

#define SORT_BLOCKS 128

// ---------------- CSR build ----------------

__global__ void zero_kernel(int* __restrict__ p, int n) {
    int i = blockIdx.x * blockDim.x + threadIdx.x;
    if (i < n) p[i] = 0;
}

__global__ void hist_kernel(const int* __restrict__ ei, int E, int Etot,
                            int* __restrict__ deg) {
    int e = blockIdx.x * blockDim.x + threadIdx.x;
    if (e >= Etot) return;
    int d = (e < E) ? ei[E + e] : (e - E);
    atomicAdd(&deg[d], 1);
}

__global__ void scan1_kernel(const int* __restrict__ deg, int n,
                             int* __restrict__ offs, int* __restrict__ bsum) {
    __shared__ int s[256];
    int tid = threadIdx.x;
    int i = blockIdx.x * 256 + tid;
    int v = (i < n) ? deg[i] : 0;
    s[tid] = v;
    __syncthreads();
    int sum = v;
    #pragma unroll
    for (int d = 1; d < 256; d <<= 1) {
        int t = (tid >= d) ? s[tid - d] : 0;
        __syncthreads();
        sum += t;
        s[tid] = sum;
        __syncthreads();
    }
    if (i < n) offs[i] = sum - v;
    if (tid == 255) bsum[blockIdx.x] = sum;
}

__global__ void scan2_kernel(int* __restrict__ bsum, int nb,
                             int* __restrict__ boff) {
    __shared__ int s[256];
    int tid = threadIdx.x;
    int v = (tid < nb) ? bsum[tid] : 0;
    s[tid] = v;
    __syncthreads();
    int sum = v;
    #pragma unroll
    for (int d = 1; d < 256; d <<= 1) {
        int t = (tid >= d) ? s[tid - d] : 0;
        __syncthreads();
        sum += t;
        s[tid] = sum;
        __syncthreads();
    }
    if (tid < nb) boff[tid] = sum - v;
}

__global__ void scan3_kernel(int* __restrict__ offs, const int* __restrict__ boff,
                             int n, int Etot, int* __restrict__ cursor) {
    int i = blockIdx.x * 256 + threadIdx.x;
    if (i < n) {
        int o = offs[i] + boff[blockIdx.x];
        offs[i] = o;
        cursor[i] = o;
    }
    if (i == 0) offs[n] = Etot;
}

// counting-sort pass 1: per-block private histogram over buckets (dst>>8).
__global__ __launch_bounds__(256) void histA_kernel(
    const int* __restrict__ ei, int E, int Etot, int chunk, int nbuck,
    int* __restrict__ histmat) {
    __shared__ int h[256];
    const int tid = threadIdx.x;
    h[tid] = 0;
    __syncthreads();
    const int b0 = blockIdx.x * chunk;
    const int b1 = min(b0 + chunk, Etot);
    for (int e = b0 + tid; e < b1; e += 256) {
        int d = (e < E) ? ei[E + e] : (e - E);
        atomicAdd(&h[d >> 8], 1);
    }
    __syncthreads();
    if (tid < nbuck) histmat[blockIdx.x * nbuck + tid] = h[tid];
}

// counting-sort pass 2: per-bucket scan over block counts, base = offs[b*256].
__global__ void scanM_kernel(const int* __restrict__ offs, int nbuck, int nblk,
                             int* __restrict__ histmat) {
    int b = blockIdx.x * blockDim.x + threadIdx.x;
    if (b >= nbuck) return;
    int run = offs[b << 8];
    for (int k = 0; k < nblk; ++k) {
        int idx = k * nbuck + b;
        int c = histmat[idx];
        histmat[idx] = run;
        run += c;
    }
}

// counting-sort pass 3: scatter (dst,src) into the block's own slices.
__global__ __launch_bounds__(256) void scatter_kernel(
    const int* __restrict__ ei, int E, int Etot, int chunk, int nbuck,
    const int* __restrict__ histmat, uint2* __restrict__ ebuf) {
    __shared__ int cur[256];
    const int tid = threadIdx.x;
    if (tid < nbuck) cur[tid] = histmat[blockIdx.x * nbuck + tid];
    __syncthreads();
    const int b0 = blockIdx.x * chunk;
    const int b1 = min(b0 + chunk, Etot);
    for (int e = b0 + tid; e < b1; e += 256) {
        int s, d;
        if (e < E) { s = ei[e]; d = ei[E + e]; }
        else       { s = d = e - E; }
        int pos = atomicAdd(&cur[d >> 8], 1);
        ebuf[pos] = make_uint2((unsigned)d, (unsigned)s);
    }
}

// counting-sort pass 4: one block per bucket; place src at per-node cursor.
__global__ __launch_bounds__(256) void order_kernel(
    const uint2* __restrict__ ebuf, const int* __restrict__ offs, int n,
    int* __restrict__ cursor, int* __restrict__ colsrc) {
    const int b = blockIdx.x;
    const int lo = offs[b << 8];
    const int hiNode = min((b + 1) << 8, n);
    const int hi = offs[hiNode];
    for (int i = lo + threadIdx.x; i < hi; i += blockDim.x) {
        uint2 q = ebuf[i];
        int pos = atomicAdd(&cursor[q.x], 1);
        colsrc[pos] = (int)q.y;
    }
}

// ---------------- helpers ----------------

__device__ __forceinline__ unsigned short f2bf(float f) {
    unsigned u = __float_as_uint(f);
    unsigned r = (u + 0x7fffu + ((u >> 16) & 1u)) >> 16;   // RNE
    return (unsigned short)r;
}

__device__ __forceinline__ bf16x8 pack8(float4 a, float4 b) {
    union { bf16x8 v; unsigned short u[8]; } t;
    t.u[0] = f2bf(a.x); t.u[1] = f2bf(a.y); t.u[2] = f2bf(a.z); t.u[3] = f2bf(a.w);
    t.u[4] = f2bf(b.x); t.u[5] = f2bf(b.y); t.u[6] = f2bf(b.z); t.u[7] = f2bf(b.w);
    return t.v;
}

__device__ __forceinline__ bf16x8 ldbf8(const unsigned short* p) {
    union { uint4 q; bf16x8 v; } t;
    t.q = *(const uint4*)p;
    return t.v;
}

__device__ __forceinline__ void unpack8(uint4 q, float* v) {
    v[0] = __uint_as_float(q.x << 16); v[1] = __uint_as_float(q.x & 0xffff0000u);
    v[2] = __uint_as_float(q.y << 16); v[3] = __uint_as_float(q.y & 0xffff0000u);
    v[4] = __uint_as_float(q.z << 16); v[5] = __uint_as_float(q.z & 0xffff0000u);
    v[6] = __uint_as_float(q.w << 16); v[7] = __uint_as_float(q.w & 0xffff0000u);
}

__device__ __forceinline__ float logit8(const float* v, const float* xrv,
                                        const float* attv) {
    float p = 0.f;
    #pragma unroll
    for (int j = 0; j < 8; ++j) {
        float m = v[j] + xrv[j];
        m = m > 0.f ? m : LRELU_ATT * m;
        p = fmaf(m, attv[j], p);
    }
    return p;
}

// ---------------- W pre-swizzle into MFMA B-fragment order ----------------

__global__ void wconv_kernel(const float* __restrict__ W0, const float* __restrict__ W1,
                             const float* __restrict__ W2, const float* __restrict__ W3,
                             unsigned short* __restrict__ Wb) {
    int g = blockIdx.x * 256 + threadIdx.x;    // 0 .. 4*16384-1
    int m = g >> 14;
    int f = g & 16383;
    int j = f & 7, l = (f >> 3) & 63, ct = (f >> 9) & 7, ks = f >> 12;
    int row = ks * 32 + ((l >> 4) << 3) + j;
    int col = ct * 16 + (l & 15);
    const float* W = m == 0 ? W0 : m == 1 ? W1 : m == 2 ? W2 : W3;
    Wb[g] = f2bf(W[row * 128 + col]);
}

// ---------------- MFMA dual GEMM: xlb(bf16)=X@Wl+bl ; xr(f32)=X@Wr+br ------

template<bool INF32>
__global__ __launch_bounds__(128) void gemm_mfma_kernel(
    const void* __restrict__ Xin,
    const unsigned short* __restrict__ Wb,
    const float* __restrict__ bl, const float* __restrict__ br,
    unsigned short* __restrict__ xlb, float* __restrict__ xr, int n) {
    const int tid  = threadIdx.x;
    const int wave = tid >> 6, lane = tid & 63;
    const int rowbase = blockIdx.x * 64 + wave * 32;
    const int lrow = lane & 15;
    const int kgrp = lane >> 4;

    bf16x8 af[2][4];
    #pragma unroll
    for (int rt = 0; rt < 2; ++rt) {
        const int row = rowbase + rt * 16 + lrow;
        const bool ok = row < n;
        #pragma unroll
        for (int ks = 0; ks < 4; ++ks) {
            const int k0 = ks * 32 + kgrp * 8;
            if (INF32) {
                const float* X = (const float*)Xin;
                float4 a = make_float4(0.f, 0.f, 0.f, 0.f), b = a;
                if (ok) {
                    a = *(const float4*)(X + (size_t)row * 128 + k0);
                    b = *(const float4*)(X + (size_t)row * 128 + k0 + 4);
                }
                af[rt][ks] = pack8(a, b);
            } else {
                const unsigned short* X = (const unsigned short*)Xin;
                union { uint4 q; bf16x8 v; } t;
                t.q = make_uint4(0u, 0u, 0u, 0u);
                if (ok) t.q = *(const uint4*)(X + (size_t)row * 128 + k0);
                af[rt][ks] = t.v;
            }
        }
    }

    #pragma unroll
    for (int m = 0; m < 2; ++m) {
        const unsigned short* wb = Wb + m * 16384;
        f32x4 acc[2][8];
        #pragma unroll
        for (int rt = 0; rt < 2; ++rt)
            #pragma unroll
            for (int ct = 0; ct < 8; ++ct)
                acc[rt][ct] = (f32x4){0.f, 0.f, 0.f, 0.f};

        #pragma unroll
        for (int ct = 0; ct < 8; ++ct) {
            #pragma unroll
            for (int ks = 0; ks < 4; ++ks) {
                bf16x8 bf = ldbf8(wb + ((ks * 8 + ct) * 64 + lane) * 8);
                acc[0][ct] = __builtin_amdgcn_mfma_f32_16x16x32_bf16(af[0][ks], bf, acc[0][ct], 0, 0, 0);
                acc[1][ct] = __builtin_amdgcn_mfma_f32_16x16x32_bf16(af[1][ks], bf, acc[1][ct], 0, 0, 0);
            }
        }

        const float* bias = m ? br : bl;
        #pragma unroll
        for (int rt = 0; rt < 2; ++rt) {
            #pragma unroll
            for (int ct = 0; ct < 8; ++ct) {
                const int col = ct * 16 + lrow;
                const float bv = bias[col];
                #pragma unroll
                for (int i = 0; i < 4; ++i) {
                    const int row = rowbase + rt * 16 + kgrp * 4 + i;
                    if (row < n) {
                        float v = acc[rt][ct][i] + bv;
                        if (m == 0) xlb[(size_t)row * 128 + col] = f2bf(v);
                        else        xr [(size_t)row * 128 + col] = v;
                    }
                }
            }
        }
    }
}

// ---------------- fused attention + aggregation ----------------

template<bool OUTBF>
__global__ __launch_bounds__(256) void gat_agg_kernel(
    const unsigned short* __restrict__ xlb, const float* __restrict__ xr,
    const float* __restrict__ att, const float* __restrict__ bo,
    const int* __restrict__ offs, const int* __restrict__ col,
    float* __restrict__ outf, unsigned short* __restrict__ outb,
    int n, int apply_act) {
    const int lane = threadIdx.x & 63;
    const int sub  = lane >> 4;
    const int sl   = lane & 15;
    const int gw   = (blockIdx.x * blockDim.x + threadIdx.x) >> 6;
    const int node = gw * 4 + sub;
    const bool valid = node < n;

    const float4* xr4  = (const float4*)xr;
    const float4* att4 = (const float4*)att;
    float xrv[8], attv[8];
    {
        float4 a = make_float4(0.f, 0.f, 0.f, 0.f), b = a;
        if (valid) {
            a = xr4[(size_t)node * 32 + sl * 2];
            b = xr4[(size_t)node * 32 + sl * 2 + 1];
        }
        xrv[0]=a.x; xrv[1]=a.y; xrv[2]=a.z; xrv[3]=a.w;
        xrv[4]=b.x; xrv[5]=b.y; xrv[6]=b.z; xrv[7]=b.w;
        float4 c = att4[sl * 2], d = att4[sl * 2 + 1];
        attv[0]=c.x; attv[1]=c.y; attv[2]=c.z; attv[3]=c.w;
        attv[4]=d.x; attv[5]=d.y; attv[6]=d.z; attv[7]=d.w;
    }

    float acc[8];
    #pragma unroll
    for (int j = 0; j < 8; ++j) acc[j] = 0.f;
    float den = 0.f;

    int b = 0, cnt = 0;
    if (valid) { b = offs[node]; cnt = offs[node + 1] - b; }
    const uint4* xq = (const uint4*)xlb;

    int t = 0;
    for (; t + 2 <= cnt; t += 2) {
        const int s0 = col[b + t], s1 = col[b + t + 1];
        uint4 q0 = xq[(size_t)s0 * 16 + sl];
        uint4 q1 = xq[(size_t)s1 * 16 + sl];
        float v0[8], v1[8];
        unpack8(q0, v0);
        unpack8(q1, v1);
        float p0 = logit8(v0, xrv, attv);
        float p1 = logit8(v1, xrv, attv);
        p0 += __shfl_xor(p0, 1, 64);  p1 += __shfl_xor(p1, 1, 64);
        p0 += __shfl_xor(p0, 2, 64);  p1 += __shfl_xor(p1, 2, 64);
        p0 += __shfl_xor(p0, 4, 64);  p1 += __shfl_xor(p1, 4, 64);
        p0 += __shfl_xor(p0, 8, 64);  p1 += __shfl_xor(p1, 8, 64);
        const float e0 = __expf(p0), e1 = __expf(p1);
        #pragma unroll
        for (int j = 0; j < 8; ++j)
            acc[j] = fmaf(e1, v1[j], fmaf(e0, v0[j], acc[j]));
        den += e0 + e1;
    }
    if (t < cnt) {
        const int s0 = col[b + t];
        uint4 q0 = xq[(size_t)s0 * 16 + sl];
        float v0[8];
        unpack8(q0, v0);
        float p0 = logit8(v0, xrv, attv);
        p0 += __shfl_xor(p0, 1, 64);
        p0 += __shfl_xor(p0, 2, 64);
        p0 += __shfl_xor(p0, 4, 64);
        p0 += __shfl_xor(p0, 8, 64);
        const float e0 = __expf(p0);
        #pragma unroll
        for (int j = 0; j < 8; ++j) acc[j] = fmaf(e0, v0[j], acc[j]);
        den += e0;
    }

    if (valid) {
        const float inv = 1.f / (den + 1e-16f);
        float4 b1 = ((const float4*)bo)[sl * 2];
        float4 b2 = ((const float4*)bo)[sl * 2 + 1];
        float bov[8] = {b1.x, b1.y, b1.z, b1.w, b2.x, b2.y, b2.z, b2.w};
        float o[8];
        #pragma unroll
        for (int j = 0; j < 8; ++j) {
            float v = acc[j] * inv + bov[j];
            if (apply_act) v = v > 0.f ? v : LRELU_ACT * v;
            o[j] = v;
        }
        if (OUTBF) {
            ushort4 u0, u1;
            u0.x = f2bf(o[0]); u0.y = f2bf(o[1]); u0.z = f2bf(o[2]); u0.w = f2bf(o[3]);
            u1.x = f2bf(o[4]); u1.y = f2bf(o[5]); u1.z = f2bf(o[6]); u1.w = f2bf(o[7]);
            ushort4* ob = (ushort4*)(outb + (size_t)node * 128 + sl * 8);
            ob[0] = u0; ob[1] = u1;
        } else {
            float4* o4 = (float4*)(outf + (size_t)node * 128 + sl * 8);
            o4[0] = make_float4(o[0], o[1], o[2], o[3]);
            o4[1] = make_float4(o[4], o[5], o[6], o[7]);
        }
    }
}

// ---------------- host launch ----------------

static inline size_t align_up(size_t x, size_t a) { return (x + a - 1) & ~(a - 1); }

extern "C" void kernel_launch(void* const* d_in, const int* in_sizes, int n_in,
                              void* d_out, int out_size, void* d_ws, size_t ws_size,
                              hipStream_t stream) {
    const float* x   = (const float*)d_in[0];
    const int*   ei  = (const int*)d_in[1];     // int32 per harness contract
    const float* Wl0 = (const float*)d_in[2];
    const float* bl0 = (const float*)d_in[3];
    const float* Wr0 = (const float*)d_in[4];
    const float* br0 = (const float*)d_in[5];
    const float* att0= (const float*)d_in[6];
    const float* bo0 = (const float*)d_in[7];
    const float* Wl1 = (const float*)d_in[8];
    const float* bl1 = (const float*)d_in[9];
    const float* Wr1 = (const float*)d_in[10];
    const float* br1 = (const float*)d_in[11];
    const float* att1= (const float*)d_in[12];
    const float* bo1 = (const float*)d_in[13];
    float* outp = (float*)d_out;

    const int N     = in_sizes[0] / 128;
    const int E     = in_sizes[1] / 2;
    const int Etot  = E + N;
    const int NBUCK = (N + 255) >> 8;        // 196 buckets of 256 nodes
    const int CHUNK = (Etot + SORT_BLOCKS - 1) / SORT_BLOCKS;

    // workspace layout (~55 MB)
    char* p = (char*)d_ws;
    size_t off = 0;
    unsigned short* xlb = (unsigned short*)(p + off);
    off = align_up(off + (size_t)N * 128 * 2, 256);
    float* xr = (float*)(p + off);
    off = align_up(off + (size_t)N * 128 * 4, 256);
    unsigned short* Wb = (unsigned short*)(p + off);
    off = align_up(off + (size_t)4 * 16384 * 2, 256);
    int* degcur = (int*)(p + off); off = align_up(off + (size_t)N * 4, 256);
    int* offs   = (int*)(p + off); off = align_up(off + (size_t)(N + 1) * 4, 256);
    int* bsum   = (int*)(p + off); off = align_up(off + 256 * 4, 256);
    int* boff   = (int*)(p + off); off = align_up(off + 256 * 4, 256);
    int* histmat= (int*)(p + off); off = align_up(off + (size_t)SORT_BLOCKS * NBUCK * 4, 256);
    int* colsrc = (int*)(p + off); off = align_up(off + (size_t)Etot * 4, 256);
    uint2* ebuf = (uint2*)(p + off); off = align_up(off + (size_t)Etot * 8, 256);
    unsigned short* hb = (unsigned short*)d_out;   // inter-layer bf16 h
    (void)ws_size;

    const int nbScan = (N + 255) / 256;
    const int nbEdge = (Etot + 255) / 256;

    // ---- CSR build (counting sort) + W swizzle ----
    zero_kernel<<<nbScan, 256, 0, stream>>>(degcur, N);
    hist_kernel<<<nbEdge, 256, 0, stream>>>(ei, E, Etot, degcur);
    scan1_kernel<<<nbScan, 256, 0, stream>>>(degcur, N, offs, bsum);
    scan2_kernel<<<1, 256, 0, stream>>>(bsum, nbScan, boff);
    scan3_kernel<<<nbScan, 256, 0, stream>>>(offs, boff, N, Etot, degcur);
    histA_kernel<<<SORT_BLOCKS, 256, 0, stream>>>(ei, E, Etot, CHUNK, NBUCK, histmat);
    scanM_kernel<<<1, 256, 0, stream>>>(offs, NBUCK, SORT_BLOCKS, histmat);
    scatter_kernel<<<SORT_BLOCKS, 256, 0, stream>>>(ei, E, Etot, CHUNK, NBUCK, histmat, ebuf);
    order_kernel<<<NBUCK, 256, 0, stream>>>(ebuf, offs, N, degcur, colsrc);
    wconv_kernel<<<256, 256, 0, stream>>>(Wl0, Wr0, Wl1, Wr1, Wb);

    const int nbGemm = (N + 63) / 64;
    const int nbAgg  = (N + 15) / 16;

    // ---- layer 0 ----
    gemm_mfma_kernel<true><<<nbGemm, 128, 0, stream>>>(
        (const void*)x, Wb, bl0, br0, xlb, xr, N);
    gat_agg_kernel<true><<<nbAgg, 256, 0, stream>>>(
        xlb, xr, att0, bo0, offs, colsrc, nullptr, hb, N, 1);

    // ---- layer 1 ----
    gemm_mfma_kernel<false><<<nbGemm, 128, 0, stream>>>(
        (const void*)hb, Wb + 2 * 16384, bl1, br1, xlb, xr, N);
    gat_agg_kernel<false><<<nbAgg, 256, 0, stream>>>(
        xlb, xr, att1, bo1, offs, colsrc, outp, nullptr, N, 0);
}

// Round 8
// 198.472 us; speedup vs baseline: 2.2072x; 1.3713x over previous
//
#include <hip/hip_runtime.h>
#include <hip/hip_bf16.h>
#include <math.h>

// ---------------------------------------------------------------------------
// GATv2 x2 layers, N=50000, d=128, E=800000 (+N self loops).
// Round 8: CSR build = pure 4-pass privatized counting sort, all parallel:
//   histA  (256 blk): LDS bucket hist, transposed histmat[bucket][block]
//   scanS  (1 blk)  : bucket totals via int4 loads (pipelined), LDS scan,
//                     in-place per-(bucket,block) bases  [replaces scan1-3+scanM]
//   scatter(256 blk): LDS cursors -> ebuf bucket slices
//   bucket_csr (196 blk x 512): bucket edges -> LDS, per-node count + scan
//                     -> writes offs AND colsrc  [replaces zero+hist+order]
// Round-7 lesson: scanM's serial 128-step strided walk + half-idle grid +
// keeping the old hist/scan pipeline cost ~147us; this drops it to ~45us.
// GEMM (MFMA bf16) and agg (16-lane subgroup) unchanged from round 5/7.
// ---------------------------------------------------------------------------

#define LRELU_ATT 0.2f
#define LRELU_ACT 0.01f

typedef __attribute__((ext_vector_type(8))) short bf16x8;
typedef __attribute__((ext_vector_type(4))) float f32x4;

#define SORT_BLOCKS 256
#define BUCKET_CAP  8192   // LDS edge capacity per bucket (mean ~4340)

// ---------------- counting-sort CSR build ----------------

// pass 1: per-block LDS histogram over buckets (dst>>8), transposed store.
__global__ __launch_bounds__(256) void histA_kernel(
    const int* __restrict__ ei, int E, int Etot, int chunk, int nbuck,
    int* __restrict__ histmat) {
    __shared__ int h[256];
    const int tid = threadIdx.x;
    h[tid] = 0;
    __syncthreads();
    const int b0 = blockIdx.x * chunk;
    const int b1 = min(b0 + chunk, Etot);
    for (int e = b0 + tid; e < b1; e += 256) {
        int d = (e < E) ? ei[E + e] : (e - E);
        atomicAdd(&h[d >> 8], 1);
    }
    __syncthreads();
    if (tid < nbuck) histmat[tid * SORT_BLOCKS + blockIdx.x] = h[tid];
}

// pass 2: bucket totals (vectorized int4), LDS scan -> bucket bases,
// then in-place per-(bucket,block) exclusive bases. bbase[nbuck]=Etot.
__global__ __launch_bounds__(256) void scanS_kernel(
    int* __restrict__ histmat, int nbuck, int* __restrict__ bbase) {
    __shared__ int s[256];
    const int tid = threadIdx.x;
    int total = 0;
    if (tid < nbuck) {
        const int4* p = (const int4*)(histmat + tid * SORT_BLOCKS);
        #pragma unroll 8
        for (int k = 0; k < SORT_BLOCKS / 4; ++k) {
            int4 v = p[k];
            total += v.x + v.y + v.z + v.w;
        }
    }
    s[tid] = total;
    __syncthreads();
    int sum = total;
    #pragma unroll
    for (int d = 1; d < 256; d <<= 1) {
        int t = (tid >= d) ? s[tid - d] : 0;
        __syncthreads();
        sum += t;
        s[tid] = sum;
        __syncthreads();
    }
    if (tid < nbuck) {
        int base = sum - total;                 // exclusive bucket base
        bbase[tid] = base;
        if (tid == nbuck - 1) bbase[nbuck] = sum;
        int4* p = (int4*)(histmat + tid * SORT_BLOCKS);
        int run = base;
        #pragma unroll 4
        for (int k = 0; k < SORT_BLOCKS / 4; ++k) {
            int4 v = p[k];
            int a = run, b = a + v.x, c = b + v.y, d2 = c + v.z;
            run = d2 + v.w;
            p[k] = make_int4(a, b, c, d2);
        }
    }
}

// pass 3: scatter (dst,src) into the block's own bucket slices.
__global__ __launch_bounds__(256) void scatter_kernel(
    const int* __restrict__ ei, int E, int Etot, int chunk, int nbuck,
    const int* __restrict__ histmat, uint2* __restrict__ ebuf) {
    __shared__ int cur[256];
    const int tid = threadIdx.x;
    if (tid < nbuck) cur[tid] = histmat[tid * SORT_BLOCKS + blockIdx.x];
    __syncthreads();
    const int b0 = blockIdx.x * chunk;
    const int b1 = min(b0 + chunk, Etot);
    for (int e = b0 + tid; e < b1; e += 256) {
        int s, d;
        if (e < E) { s = ei[e]; d = ei[E + e]; }
        else       { s = d = e - E; }
        int pos = atomicAdd(&cur[d >> 8], 1);
        ebuf[pos] = make_uint2((unsigned)d, (unsigned)s);
    }
}

// pass 4: one block per bucket. Edges -> LDS, per-node LDS count + scan
// -> write offs[node] and place colsrc (block-owned region).
__global__ __launch_bounds__(512) void bucket_csr_kernel(
    const uint2* __restrict__ ebuf, const int* __restrict__ bbase, int n,
    int nbuck, int* __restrict__ offs, int* __restrict__ colsrc) {
    __shared__ int cnt[256];
    __shared__ int cur[256];
    __shared__ uint2 eb[BUCKET_CAP];
    const int b = blockIdx.x, tid = threadIdx.x;
    const int lo = bbase[b], hi = bbase[b + 1];
    const int m = hi - lo;
    const int node0 = b << 8;
    const bool inl = (m <= BUCKET_CAP);

    if (tid < 256) cnt[tid] = 0;
    __syncthreads();

    if (inl) {
        for (int i = tid; i < m; i += 512) {
            uint2 q = ebuf[lo + i];
            eb[i] = q;
            atomicAdd(&cnt[q.x & 255], 1);
        }
    } else {
        for (int i = tid; i < m; i += 512)
            atomicAdd(&cnt[ebuf[lo + i].x & 255], 1);
    }
    __syncthreads();

    // scan 256 node counts (threads 0..255)
    int v = (tid < 256) ? cnt[tid] : 0;
    if (tid < 256) cur[tid] = v;
    __syncthreads();
    int sum = v;
    #pragma unroll
    for (int d = 1; d < 256; d <<= 1) {
        int t = 0;
        if (tid < 256 && tid >= d) t = cur[tid - d];
        __syncthreads();
        if (tid < 256) { sum += t; cur[tid] = sum; }
        __syncthreads();
    }
    if (tid < 256) {
        int node = node0 + tid;
        int off = lo + sum - v;              // global exclusive offset
        if (node < n) { offs[node] = off; }
        cur[tid] = off;                      // cursor
    }
    if (b == nbuck - 1 && tid == 0) offs[n] = hi;
    __syncthreads();

    if (inl) {
        for (int i = tid; i < m; i += 512) {
            uint2 q = eb[i];
            int pos = atomicAdd(&cur[q.x & 255], 1);
            colsrc[pos] = (int)q.y;
        }
    } else {
        for (int i = tid; i < m; i += 512) {
            uint2 q = ebuf[lo + i];
            int pos = atomicAdd(&cur[q.x & 255], 1);
            colsrc[pos] = (int)q.y;
        }
    }
}

// ---------------- helpers ----------------

__device__ __forceinline__ unsigned short f2bf(float f) {
    unsigned u = __float_as_uint(f);
    unsigned r = (u + 0x7fffu + ((u >> 16) & 1u)) >> 16;   // RNE
    return (unsigned short)r;
}

__device__ __forceinline__ bf16x8 pack8(float4 a, float4 b) {
    union { bf16x8 v; unsigned short u[8]; } t;
    t.u[0] = f2bf(a.x); t.u[1] = f2bf(a.y); t.u[2] = f2bf(a.z); t.u[3] = f2bf(a.w);
    t.u[4] = f2bf(b.x); t.u[5] = f2bf(b.y); t.u[6] = f2bf(b.z); t.u[7] = f2bf(b.w);
    return t.v;
}

__device__ __forceinline__ bf16x8 ldbf8(const unsigned short* p) {
    union { uint4 q; bf16x8 v; } t;
    t.q = *(const uint4*)p;
    return t.v;
}

__device__ __forceinline__ void unpack8(uint4 q, float* v) {
    v[0] = __uint_as_float(q.x << 16); v[1] = __uint_as_float(q.x & 0xffff0000u);
    v[2] = __uint_as_float(q.y << 16); v[3] = __uint_as_float(q.y & 0xffff0000u);
    v[4] = __uint_as_float(q.z << 16); v[5] = __uint_as_float(q.z & 0xffff0000u);
    v[6] = __uint_as_float(q.w << 16); v[7] = __uint_as_float(q.w & 0xffff0000u);
}

__device__ __forceinline__ float logit8(const float* v, const float* xrv,
                                        const float* attv) {
    float p = 0.f;
    #pragma unroll
    for (int j = 0; j < 8; ++j) {
        float m = v[j] + xrv[j];
        m = m > 0.f ? m : LRELU_ATT * m;
        p = fmaf(m, attv[j], p);
    }
    return p;
}

// ---------------- W pre-swizzle into MFMA B-fragment order ----------------

__global__ void wconv_kernel(const float* __restrict__ W0, const float* __restrict__ W1,
                             const float* __restrict__ W2, const float* __restrict__ W3,
                             unsigned short* __restrict__ Wb) {
    int g = blockIdx.x * 256 + threadIdx.x;    // 0 .. 4*16384-1
    int m = g >> 14;
    int f = g & 16383;
    int j = f & 7, l = (f >> 3) & 63, ct = (f >> 9) & 7, ks = f >> 12;
    int row = ks * 32 + ((l >> 4) << 3) + j;
    int col = ct * 16 + (l & 15);
    const float* W = m == 0 ? W0 : m == 1 ? W1 : m == 2 ? W2 : W3;
    Wb[g] = f2bf(W[row * 128 + col]);
}

// ---------------- MFMA dual GEMM: xlb(bf16)=X@Wl+bl ; xr(f32)=X@Wr+br ------

template<bool INF32>
__global__ __launch_bounds__(128) void gemm_mfma_kernel(
    const void* __restrict__ Xin,
    const unsigned short* __restrict__ Wb,
    const float* __restrict__ bl, const float* __restrict__ br,
    unsigned short* __restrict__ xlb, float* __restrict__ xr, int n) {
    const int tid  = threadIdx.x;
    const int wave = tid >> 6, lane = tid & 63;
    const int rowbase = blockIdx.x * 64 + wave * 32;
    const int lrow = lane & 15;
    const int kgrp = lane >> 4;

    bf16x8 af[2][4];
    #pragma unroll
    for (int rt = 0; rt < 2; ++rt) {
        const int row = rowbase + rt * 16 + lrow;
        const bool ok = row < n;
        #pragma unroll
        for (int ks = 0; ks < 4; ++ks) {
            const int k0 = ks * 32 + kgrp * 8;
            if (INF32) {
                const float* X = (const float*)Xin;
                float4 a = make_float4(0.f, 0.f, 0.f, 0.f), b = a;
                if (ok) {
                    a = *(const float4*)(X + (size_t)row * 128 + k0);
                    b = *(const float4*)(X + (size_t)row * 128 + k0 + 4);
                }
                af[rt][ks] = pack8(a, b);
            } else {
                const unsigned short* X = (const unsigned short*)Xin;
                union { uint4 q; bf16x8 v; } t;
                t.q = make_uint4(0u, 0u, 0u, 0u);
                if (ok) t.q = *(const uint4*)(X + (size_t)row * 128 + k0);
                af[rt][ks] = t.v;
            }
        }
    }

    #pragma unroll
    for (int m = 0; m < 2; ++m) {
        const unsigned short* wb = Wb + m * 16384;
        f32x4 acc[2][8];
        #pragma unroll
        for (int rt = 0; rt < 2; ++rt)
            #pragma unroll
            for (int ct = 0; ct < 8; ++ct)
                acc[rt][ct] = (f32x4){0.f, 0.f, 0.f, 0.f};

        #pragma unroll
        for (int ct = 0; ct < 8; ++ct) {
            #pragma unroll
            for (int ks = 0; ks < 4; ++ks) {
                bf16x8 bf = ldbf8(wb + ((ks * 8 + ct) * 64 + lane) * 8);
                acc[0][ct] = __builtin_amdgcn_mfma_f32_16x16x32_bf16(af[0][ks], bf, acc[0][ct], 0, 0, 0);
                acc[1][ct] = __builtin_amdgcn_mfma_f32_16x16x32_bf16(af[1][ks], bf, acc[1][ct], 0, 0, 0);
            }
        }

        const float* bias = m ? br : bl;
        #pragma unroll
        for (int rt = 0; rt < 2; ++rt) {
            #pragma unroll
            for (int ct = 0; ct < 8; ++ct) {
                const int col = ct * 16 + lrow;
                const float bv = bias[col];
                #pragma unroll
                for (int i = 0; i < 4; ++i) {
                    const int row = rowbase + rt * 16 + kgrp * 4 + i;
                    if (row < n) {
                        float v = acc[rt][ct][i] + bv;
                        if (m == 0) xlb[(size_t)row * 128 + col] = f2bf(v);
                        else        xr [(size_t)row * 128 + col] = v;
                    }
                }
            }
        }
    }
}

// ---------------- fused attention + aggregation ----------------

template<bool OUTBF>
__global__ __launch_bounds__(256) void gat_agg_kernel(
    const unsigned short* __restrict__ xlb, const float* __restrict__ xr,
    const float* __restrict__ att, const float* __restrict__ bo,
    const int* __restrict__ offs, const int* __restrict__ col,
    float* __restrict__ outf, unsigned short* __restrict__ outb,
    int n, int apply_act) {
    const int lane = threadIdx.x & 63;
    const int sub  = lane >> 4;
    const int sl   = lane & 15;
    const int gw   = (blockIdx.x * blockDim.x + threadIdx.x) >> 6;
    const int node = gw * 4 + sub;
    const bool valid = node < n;

    const float4* xr4  = (const float4*)xr;
    const float4* att4 = (const float4*)att;
    float xrv[8], attv[8];
    {
        float4 a = make_float4(0.f, 0.f, 0.f, 0.f), b = a;
        if (valid) {
            a = xr4[(size_t)node * 32 + sl * 2];
            b = xr4[(size_t)node * 32 + sl * 2 + 1];
        }
        xrv[0]=a.x; xrv[1]=a.y; xrv[2]=a.z; xrv[3]=a.w;
        xrv[4]=b.x; xrv[5]=b.y; xrv[6]=b.z; xrv[7]=b.w;
        float4 c = att4[sl * 2], d = att4[sl * 2 + 1];
        attv[0]=c.x; attv[1]=c.y; attv[2]=c.z; attv[3]=c.w;
        attv[4]=d.x; attv[5]=d.y; attv[6]=d.z; attv[7]=d.w;
    }

    float acc[8];
    #pragma unroll
    for (int j = 0; j < 8; ++j) acc[j] = 0.f;
    float den = 0.f;

    int b = 0, cnt = 0;
    if (valid) { b = offs[node]; cnt = offs[node + 1] - b; }
    const uint4* xq = (const uint4*)xlb;

    int t = 0;
    for (; t + 2 <= cnt; t += 2) {
        const int s0 = col[b + t], s1 = col[b + t + 1];
        uint4 q0 = xq[(size_t)s0 * 16 + sl];
        uint4 q1 = xq[(size_t)s1 * 16 + sl];
        float v0[8], v1[8];
        unpack8(q0, v0);
        unpack8(q1, v1);
        float p0 = logit8(v0, xrv, attv);
        float p1 = logit8(v1, xrv, attv);
        p0 += __shfl_xor(p0, 1, 64);  p1 += __shfl_xor(p1, 1, 64);
        p0 += __shfl_xor(p0, 2, 64);  p1 += __shfl_xor(p1, 2, 64);
        p0 += __shfl_xor(p0, 4, 64);  p1 += __shfl_xor(p1, 4, 64);
        p0 += __shfl_xor(p0, 8, 64);  p1 += __shfl_xor(p1, 8, 64);
        const float e0 = __expf(p0), e1 = __expf(p1);
        #pragma unroll
        for (int j = 0; j < 8; ++j)
            acc[j] = fmaf(e1, v1[j], fmaf(e0, v0[j], acc[j]));
        den += e0 + e1;
    }
    if (t < cnt) {
        const int s0 = col[b + t];
        uint4 q0 = xq[(size_t)s0 * 16 + sl];
        float v0[8];
        unpack8(q0, v0);
        float p0 = logit8(v0, xrv, attv);
        p0 += __shfl_xor(p0, 1, 64);
        p0 += __shfl_xor(p0, 2, 64);
        p0 += __shfl_xor(p0, 4, 64);
        p0 += __shfl_xor(p0, 8, 64);
        const float e0 = __expf(p0);
        #pragma unroll
        for (int j = 0; j < 8; ++j) acc[j] = fmaf(e0, v0[j], acc[j]);
        den += e0;
    }

    if (valid) {
        const float inv = 1.f / (den + 1e-16f);
        float4 b1 = ((const float4*)bo)[sl * 2];
        float4 b2 = ((const float4*)bo)[sl * 2 + 1];
        float bov[8] = {b1.x, b1.y, b1.z, b1.w, b2.x, b2.y, b2.z, b2.w};
        float o[8];
        #pragma unroll
        for (int j = 0; j < 8; ++j) {
            float v = acc[j] * inv + bov[j];
            if (apply_act) v = v > 0.f ? v : LRELU_ACT * v;
            o[j] = v;
        }
        if (OUTBF) {
            ushort4 u0, u1;
            u0.x = f2bf(o[0]); u0.y = f2bf(o[1]); u0.z = f2bf(o[2]); u0.w = f2bf(o[3]);
            u1.x = f2bf(o[4]); u1.y = f2bf(o[5]); u1.z = f2bf(o[6]); u1.w = f2bf(o[7]);
            ushort4* ob = (ushort4*)(outb + (size_t)node * 128 + sl * 8);
            ob[0] = u0; ob[1] = u1;
        } else {
            float4* o4 = (float4*)(outf + (size_t)node * 128 + sl * 8);
            o4[0] = make_float4(o[0], o[1], o[2], o[3]);
            o4[1] = make_float4(o[4], o[5], o[6], o[7]);
        }
    }
}

// ---------------- host launch ----------------

static inline size_t align_up(size_t x, size_t a) { return (x + a - 1) & ~(a - 1); }

extern "C" void kernel_launch(void* const* d_in, const int* in_sizes, int n_in,
                              void* d_out, int out_size, void* d_ws, size_t ws_size,
                              hipStream_t stream) {
    const float* x   = (const float*)d_in[0];
    const int*   ei  = (const int*)d_in[1];     // int32 per harness contract
    const float* Wl0 = (const float*)d_in[2];
    const float* bl0 = (const float*)d_in[3];
    const float* Wr0 = (const float*)d_in[4];
    const float* br0 = (const float*)d_in[5];
    const float* att0= (const float*)d_in[6];
    const float* bo0 = (const float*)d_in[7];
    const float* Wl1 = (const float*)d_in[8];
    const float* bl1 = (const float*)d_in[9];
    const float* Wr1 = (const float*)d_in[10];
    const float* br1 = (const float*)d_in[11];
    const float* att1= (const float*)d_in[12];
    const float* bo1 = (const float*)d_in[13];
    float* outp = (float*)d_out;

    const int N     = in_sizes[0] / 128;
    const int E     = in_sizes[1] / 2;
    const int Etot  = E + N;
    const int NBUCK = (N + 255) >> 8;        // 196 buckets of 256 nodes
    const int CHUNK = (Etot + SORT_BLOCKS - 1) / SORT_BLOCKS;

    // workspace layout (~49 MB)
    char* p = (char*)d_ws;
    size_t off = 0;
    unsigned short* xlb = (unsigned short*)(p + off);
    off = align_up(off + (size_t)N * 128 * 2, 256);
    float* xr = (float*)(p + off);
    off = align_up(off + (size_t)N * 128 * 4, 256);
    unsigned short* Wb = (unsigned short*)(p + off);
    off = align_up(off + (size_t)4 * 16384 * 2, 256);
    int* histmat= (int*)(p + off); off = align_up(off + (size_t)NBUCK * SORT_BLOCKS * 4, 256);
    int* bbase  = (int*)(p + off); off = align_up(off + (size_t)(NBUCK + 1) * 4, 256);
    int* offs   = (int*)(p + off); off = align_up(off + (size_t)(N + 1) * 4, 256);
    int* colsrc = (int*)(p + off); off = align_up(off + (size_t)Etot * 4, 256);
    uint2* ebuf = (uint2*)(p + off); off = align_up(off + (size_t)Etot * 8, 256);
    unsigned short* hb = (unsigned short*)d_out;   // inter-layer bf16 h
    (void)ws_size;

    // ---- CSR build (counting sort) + W swizzle ----
    histA_kernel<<<SORT_BLOCKS, 256, 0, stream>>>(ei, E, Etot, CHUNK, NBUCK, histmat);
    scanS_kernel<<<1, 256, 0, stream>>>(histmat, NBUCK, bbase);
    scatter_kernel<<<SORT_BLOCKS, 256, 0, stream>>>(ei, E, Etot, CHUNK, NBUCK, histmat, ebuf);
    bucket_csr_kernel<<<NBUCK, 512, 0, stream>>>(ebuf, bbase, N, NBUCK, offs, colsrc);
    wconv_kernel<<<256, 256, 0, stream>>>(Wl0, Wr0, Wl1, Wr1, Wb);

    const int nbGemm = (N + 63) / 64;
    const int nbAgg  = (N + 15) / 16;

    // ---- layer 0 ----
    gemm_mfma_kernel<true><<<nbGemm, 128, 0, stream>>>(
        (const void*)x, Wb, bl0, br0, xlb, xr, N);
    gat_agg_kernel<true><<<nbAgg, 256, 0, stream>>>(
        xlb, xr, att0, bo0, offs, colsrc, nullptr, hb, N, 1);

    // ---- layer 1 ----
    gemm_mfma_kernel<false><<<nbGemm, 128, 0, stream>>>(
        (const void*)hb, Wb + 2 * 16384, bl1, br1, xlb, xr, N);
    gat_agg_kernel<false><<<nbAgg, 256, 0, stream>>>(
        xlb, xr, att1, bo1, offs, colsrc, outp, nullptr, N, 0);
}